// Round 2
// baseline (2984.098 us; speedup 1.0000x reference)
//
#include <hip/hip_runtime.h>

// SimpleRNN on MI355X.
// B=256, S=512, I=128, H=512, O=128, fp32 in/out, f16 MFMA internally.
//
// Design: 16 teams x 4 WGs. Team t owns batch rows [16t,16t+16).
// Member m of a team owns output slice j in [128m, 128m+128) and keeps
// W_hh[j_slice, :] resident in LDS (128x512 f16 = 128KB, XOR-swizzled).
// W_ih[j_slice, :] lives in registers as prebuilt MFMA B-fragments.
// Each step: x-projection MFMAs (no teammate dependency) -> spin on team
// flags -> acquire fence (L1/L2 inv) -> h-part MFMAs from teammates' h
// slices in global -> tanh -> publish h slice with sc0/sc1 stores ->
// barrier -> release flag.  h double-buffered; flags memset to 0 per launch.

#define B_SZ 256
#define S_SZ 512
#define I_SZ 128
#define H_SZ 512
#define O_SZ 128
#define RPT 16      // batch rows per team
#define SLICE 128   // j columns per member

typedef _Float16 f16;
typedef _Float16 f16x8 __attribute__((ext_vector_type(8)));
typedef _Float16 f16x2 __attribute__((ext_vector_type(2)));
typedef float f32x4 __attribute__((ext_vector_type(4)));

// Swizzled LDS B-fragment read: row j (0..127), 16B chunk index cc (0..63).
// Chunk is XORed with (j&7) so the 16 rows of a fragment read spread across
// all 32 banks (2-way = free).
__device__ __forceinline__ f16x8 lds_readB(const f16* sm, int j, int cc) {
    int cs = cc ^ (j & 7);
    return *(const f16x8*)(sm + j * H_SZ + cs * 8);
}

__device__ __forceinline__ f16x8 cvt8(float4 a, float4 b) {
    f16x8 r;
    f16x2 p;
    p = __builtin_bit_cast(f16x2, __builtin_amdgcn_cvt_pkrtz(a.x, a.y)); r[0] = p[0]; r[1] = p[1];
    p = __builtin_bit_cast(f16x2, __builtin_amdgcn_cvt_pkrtz(a.z, a.w)); r[2] = p[0]; r[3] = p[1];
    p = __builtin_bit_cast(f16x2, __builtin_amdgcn_cvt_pkrtz(b.x, b.y)); r[4] = p[0]; r[5] = p[1];
    p = __builtin_bit_cast(f16x2, __builtin_amdgcn_cvt_pkrtz(b.z, b.w)); r[6] = p[0]; r[7] = p[1];
    return r;
}

__global__ __launch_bounds__(256) void rnn_kernel(
    const float* __restrict__ x, const float* __restrict__ Wih,
    const float* __restrict__ Whh, const float* __restrict__ bih,
    const float* __restrict__ bhh, f16* __restrict__ hbuf,
    int* __restrict__ ready)
{
    __shared__ f16 smem[SLICE * H_SZ];   // 131072 B

    const int bid  = blockIdx.x;
    // XCD co-location: blocks {b, b+8, b+16, b+24} (same XCD under %8
    // round-robin) form one team. Correctness does not depend on this.
    const int team = ((bid >> 5) << 3) | (bid & 7);   // 0..15
    const int mem  = (bid >> 3) & 3;                  // 0..3
    const int tid  = threadIdx.x;
    const int w    = tid >> 6;        // wave 0..3
    const int lane = tid & 63;
    const int c    = lane & 15;       // MFMA row/col index
    const int g    = lane >> 4;       // k-group 0..3

    const int jg0   = mem * SLICE;    // global j base of this member
    const int jrow0 = w * 32;         // this wave's N-tile base within slice
    const int bt    = team * RPT;     // batch row base
    const int t4    = team * 4;

    // ---- stage W_hh slice into LDS (f16, 16B-chunk XOR swizzle) ----
    for (int r = 0; r < SLICE; ++r) {
        for (int k = tid; k < H_SZ; k += 256) {
            float v = Whh[(size_t)(jg0 + r) * H_SZ + k];
            smem[r * H_SZ + (((k >> 3) ^ (r & 7)) << 3) + (k & 7)] = (f16)v;
        }
    }

    // ---- W_ih slice as register-resident B-fragments ----
    // frag(nt,kx): B[k][n] with n=c (row j = jg0+jrow0+nt*16+c),
    //              k = kx*32 + g*8 + e  (input index i).
    f16x8 wx[2][4];
#pragma unroll
    for (int nt = 0; nt < 2; ++nt) {
#pragma unroll
        for (int kx = 0; kx < 4; ++kx) {
            const float* src = Wih + (size_t)(jg0 + jrow0 + nt * 16 + c) * I_SZ
                                   + kx * 32 + g * 8;
            float4 a = *(const float4*)(src);
            float4 b = *(const float4*)(src + 4);
            wx[nt][kx] = cvt8(a, b);
        }
    }

    // bias (b_ih + b_hh) for this lane's two j columns
    float biasv[2];
#pragma unroll
    for (int nt = 0; nt < 2; ++nt) {
        int j = jg0 + jrow0 + nt * 16 + c;
        biasv[nt] = bih[j] + bhh[j];
    }
    __syncthreads();

    for (int s = 0; s < S_SZ; ++s) {
        f32x4 acc0 = {0.f, 0.f, 0.f, 0.f};
        f32x4 acc1 = {0.f, 0.f, 0.f, 0.f};

        // ---- x-projection part (independent of teammates; runs pre-spin) ----
        {
            const float* xb = x + ((size_t)(bt + c) * S_SZ + s) * I_SZ;
#pragma unroll
            for (int kx = 0; kx < 4; ++kx) {
                int i0 = kx * 32 + g * 8;
                float4 va = *(const float4*)(xb + i0);
                float4 vb = *(const float4*)(xb + i0 + 4);
                f16x8 a = cvt8(va, vb);
                acc0 = __builtin_amdgcn_mfma_f32_16x16x32_f16(a, wx[0][kx], acc0, 0, 0, 0);
                acc1 = __builtin_amdgcn_mfma_f32_16x16x32_f16(a, wx[1][kx], acc1, 0, 0, 0);
            }
        }

        // ---- recurrent part ----
        if (s > 0) {
            // spin until all 4 members published h_s (ready >= s)
            const int slot = lane & 3;
            while (true) {
                int v = __hip_atomic_load(&ready[t4 + slot], __ATOMIC_RELAXED,
                                          __HIP_MEMORY_SCOPE_AGENT);
                if (__all(v >= s)) break;
                __builtin_amdgcn_s_sleep(1);
            }
            __builtin_amdgcn_fence(__ATOMIC_ACQUIRE, "agent");  // inv L1/L2

            const f16* hb = hbuf + (size_t)(s & 1) * (B_SZ * H_SZ)
                                 + (size_t)(bt + c) * H_SZ + g * 8;
            f16x8 ah[16];
#pragma unroll
            for (int kh = 0; kh < 16; ++kh)
                ah[kh] = *(const f16x8*)(hb + kh * 32);
#pragma unroll
            for (int kh = 0; kh < 16; ++kh) {
                int cc = kh * 4 + g;
                f16x8 b0 = lds_readB(smem, jrow0 + c, cc);
                f16x8 b1 = lds_readB(smem, jrow0 + 16 + c, cc);
                acc0 = __builtin_amdgcn_mfma_f32_16x16x32_f16(ah[kh], b0, acc0, 0, 0, 0);
                acc1 = __builtin_amdgcn_mfma_f32_16x16x32_f16(ah[kh], b1, acc1, 0, 0, 0);
            }
        }

        // ---- tanh + publish h_{s+1} slice ----
        {
            f16* ho = hbuf + (size_t)((s + 1) & 1) * (B_SZ * H_SZ);
#pragma unroll
            for (int nt = 0; nt < 2; ++nt) {
                f32x4 acc = nt ? acc1 : acc0;
#pragma unroll
                for (int r = 0; r < 4; ++r) {
                    float pre = acc[r] + biasv[nt];
                    float e = __expf(2.f * pre);
                    float hv = 1.f - 2.f * __builtin_amdgcn_rcpf(e + 1.f);
                    // D layout: row(b) = 4g+r, col(j) = c
                    f16* p = ho + (size_t)(bt + g * 4 + r) * H_SZ
                                + jg0 + jrow0 + nt * 16 + c;
                    unsigned short us = __builtin_bit_cast(unsigned short, (f16)hv);
                    unsigned int uu = us;
                    // write-through to coherence point (cross-XCD visible)
                    asm volatile("global_store_short %0, %1, off sc0 sc1"
                                 :: "v"(p), "v"(uu) : "memory");
                }
            }
        }
        asm volatile("s_waitcnt vmcnt(0)" ::: "memory");
        __syncthreads();
        if (tid == 0) {
            __hip_atomic_store(&ready[t4 + mem], s + 1, __ATOMIC_RELEASE,
                               __HIP_MEMORY_SCOPE_AGENT);
        }
    }
}

// out[b][o] = sum_k h[b][k] * Wfc[o][k] + bfc[o]
__global__ __launch_bounds__(128) void fc_kernel(
    const f16* __restrict__ hbuf, const float* __restrict__ Wfc,
    const float* __restrict__ bfc, float* __restrict__ out)
{
    __builtin_amdgcn_fence(__ATOMIC_ACQUIRE, "agent");  // see rnn's sc stores
    __shared__ float hs[H_SZ];
    int b = blockIdx.x, o = threadIdx.x;
    for (int k = o; k < H_SZ; k += 128)
        hs[k] = (float)hbuf[(size_t)b * H_SZ + k];
    __syncthreads();
    const float* wr = Wfc + (size_t)o * H_SZ;
    float acc = bfc[o];
#pragma unroll 8
    for (int k = 0; k < H_SZ; k += 4) {
        float4 wv = *(const float4*)(wr + k);
        acc += wv.x * hs[k] + wv.y * hs[k + 1] + wv.z * hs[k + 2] + wv.w * hs[k + 3];
    }
    out[(size_t)b * O_SZ + o] = acc;
}

extern "C" void kernel_launch(void* const* d_in, const int* in_sizes, int n_in,
                              void* d_out, int out_size, void* d_ws, size_t ws_size,
                              hipStream_t stream) {
    const float* x   = (const float*)d_in[0];
    const float* Wih = (const float*)d_in[1];
    const float* Whh = (const float*)d_in[2];
    const float* bih = (const float*)d_in[3];
    const float* bhh = (const float*)d_in[4];
    const float* Wfc = (const float*)d_in[5];
    const float* bfc = (const float*)d_in[6];
    float* out = (float*)d_out;

    int* ready = (int*)d_ws;                       // 64 ints, padded to 1KB
    f16* hbuf  = (f16*)((char*)d_ws + 1024);       // 2 x 256 x 512 f16 = 512KB

    (void)hipMemsetAsync(d_ws, 0, 1024, stream);   // zero team flags each launch
    hipLaunchKernelGGL(rnn_kernel, dim3(64), dim3(256), 0, stream,
                       x, Wih, Whh, bih, bhh, hbuf, ready);
    hipLaunchKernelGGL(fc_kernel, dim3(B_SZ), dim3(128), 0, stream,
                       hbuf, Wfc, bfc, out);
}

// Round 3
// 1396.377 us; speedup vs baseline: 2.1370x; 2.1370x over previous
//
#include <hip/hip_runtime.h>

// SimpleRNN on MI355X — round 3.
// B=256, S=512, I=128, H=512, O=128; fp32 in/out, f16 MFMA internally.
//
// 16 teams x 4 WGs (4 waves each, 1 WG/CU, 1 wave/SIMD -> 512-VGPR budget).
// Member m owns output cols [128m,128m+128); W_hh B-fragments REGISTER-
// persistent (128 VGPRs), W_ih fragments register-persistent (32 VGPRs).
// LDS = one 16KB swizzled h-stage [16 rows][512 cols].
// Per step: x-proj MFMAs + own-k MFMAs (overlap poll) -> wave0 polls padded
// flags -> coop single-copy remote load (sc0 sc1, bypass L1/L2) -> LDS stage
// -> remote-k MFMAs -> tanh -> stage own h_{s+1} -> coalesced 16B publish
// (sc0 sc1) -> vmcnt(0) -> barrier -> flag store. No cache-invalidating
// fences; coherence via per-access sc0 sc1 on the exchanged data only.

#define B_SZ 256
#define S_SZ 512
#define I_SZ 128
#define H_SZ 512
#define O_SZ 128
#define RPT 16      // batch rows per team
#define SLICE 128   // j columns per member

typedef _Float16 f16;
typedef _Float16 f16x8 __attribute__((ext_vector_type(8)));
typedef _Float16 f16x2 __attribute__((ext_vector_type(2)));
typedef float f32x4 __attribute__((ext_vector_type(4)));
typedef int i32x4 __attribute__((ext_vector_type(4)));

__device__ __forceinline__ f16x8 cvt8(float4 a, float4 b) {
    f16x8 r;
    f16x2 p;
    p = __builtin_bit_cast(f16x2, __builtin_amdgcn_cvt_pkrtz(a.x, a.y)); r[0] = p[0]; r[1] = p[1];
    p = __builtin_bit_cast(f16x2, __builtin_amdgcn_cvt_pkrtz(a.z, a.w)); r[2] = p[0]; r[3] = p[1];
    p = __builtin_bit_cast(f16x2, __builtin_amdgcn_cvt_pkrtz(b.x, b.y)); r[4] = p[0]; r[5] = p[1];
    p = __builtin_bit_cast(f16x2, __builtin_amdgcn_cvt_pkrtz(b.z, b.w)); r[6] = p[0]; r[7] = p[1];
    return r;
}

// h-stage read: row (0..15), k8 = 16B-chunk index (0..63). Swizzle: chunk
// XOR (row&7) -> 16 lanes reading 16 rows at same chunk spread 2-way (free).
__device__ __forceinline__ f16x8 readA(const f16* hs, int row, int k8) {
    int kk = k8 ^ (row & 7);
    return *(const f16x8*)(hs + row * H_SZ + kk * 8);
}

__global__ __launch_bounds__(256, 1) void rnn_kernel(
    const float* __restrict__ x, const float* __restrict__ Wih,
    const float* __restrict__ Whh, const float* __restrict__ bih,
    const float* __restrict__ bhh, f16* __restrict__ hbuf,
    int* __restrict__ ready)
{
    __shared__ f16 hstage[RPT * H_SZ];   // 16 KB, col-swizzled

    const int bid  = blockIdx.x;
    const int team = ((bid >> 5) << 3) | (bid & 7);   // 0..15 (teammates co-XCD under %8)
    const int mem  = (bid >> 3) & 3;                  // 0..3
    const int tid  = threadIdx.x;
    const int w    = tid >> 6;
    const int lane = tid & 63;
    const int c    = lane & 15;       // MFMA row/col index
    const int g    = lane >> 4;       // k-group 0..3

    const int jg0   = mem * SLICE;
    const int jrow0 = w * 32;
    const int bt    = team * RPT;
    const int tslot = team * 4;

    // publish/coop-load thread mapping: 256 threads x 16B cover 16x128 f16
    const int prow = tid >> 4;   // 0..15 batch row
    const int pcg  = tid & 15;   // 0..15 col-group of 8

    // ---- W_hh B-fragments, register-persistent, own-k-first permuted order:
    // q=0..3 -> own k-tiles (kt=mem*4+q), q=4..15 -> remote in ring order.
    f16x8 wb0[16], wb1[16];
#pragma unroll
    for (int q = 0; q < 16; ++q) {
        int kt = (((mem + (q >> 2)) & 3) << 2) + (q & 3);
        const float* s0 = Whh + (size_t)(jg0 + jrow0 + c) * H_SZ + kt * 32 + g * 8;
        const float* s1 = s0 + 16 * H_SZ;
        wb0[q] = cvt8(*(const float4*)s0, *(const float4*)(s0 + 4));
        wb1[q] = cvt8(*(const float4*)s1, *(const float4*)(s1 + 4));
    }

    // ---- W_ih B-fragments ----
    f16x8 wx0[4], wx1[4];
#pragma unroll
    for (int kx = 0; kx < 4; ++kx) {
        const float* s0 = Wih + (size_t)(jg0 + jrow0 + c) * I_SZ + kx * 32 + g * 8;
        const float* s1 = s0 + 16 * I_SZ;
        wx0[kx] = cvt8(*(const float4*)s0, *(const float4*)(s0 + 4));
        wx1[kx] = cvt8(*(const float4*)s1, *(const float4*)(s1 + 4));
    }

    float biasv[2];
#pragma unroll
    for (int nt = 0; nt < 2; ++nt)
        biasv[nt] = bih[jg0 + jrow0 + nt * 16 + c] + bhh[jg0 + jrow0 + nt * 16 + c];

    // x prefetch for s=0 (lane reads 32 consecutive f32 of its batch row)
    const float* xrow = x + (size_t)(bt + c) * S_SZ * I_SZ + g * 8;
    float4 xa[8];
#pragma unroll
    for (int kx = 0; kx < 4; ++kx) {
        xa[2 * kx]     = *(const float4*)(xrow + kx * 32);
        xa[2 * kx + 1] = *(const float4*)(xrow + kx * 32 + 4);
    }

    for (int s = 0; s < S_SZ; ++s) {
        // split accumulator chains (hide MFMA dep latency)
        f32x4 a0a = {0,0,0,0}, a0b = {0,0,0,0}, a1a = {0,0,0,0}, a1b = {0,0,0,0};

        // ---- x-projection (uses prefetched x) ----
#pragma unroll
        for (int kx = 0; kx < 4; ++kx) {
            f16x8 a = cvt8(xa[2 * kx], xa[2 * kx + 1]);
            if (kx & 1) {
                a0b = __builtin_amdgcn_mfma_f32_16x16x32_f16(a, wx0[kx], a0b, 0, 0, 0);
                a1b = __builtin_amdgcn_mfma_f32_16x16x32_f16(a, wx1[kx], a1b, 0, 0, 0);
            } else {
                a0a = __builtin_amdgcn_mfma_f32_16x16x32_f16(a, wx0[kx], a0a, 0, 0, 0);
                a1a = __builtin_amdgcn_mfma_f32_16x16x32_f16(a, wx1[kx], a1a, 0, 0, 0);
            }
        }
        // prefetch x for s+1 (in flight across exchange + MFMA phases)
        if (s + 1 < S_SZ) {
            const float* xb = xrow + (size_t)(s + 1) * I_SZ;
#pragma unroll
            for (int kx = 0; kx < 4; ++kx) {
                xa[2 * kx]     = *(const float4*)(xb + kx * 32);
                xa[2 * kx + 1] = *(const float4*)(xb + kx * 32 + 4);
            }
        }

        if (s > 0) {
            // ---- own-k MFMAs (h slice we staged last iter; overlaps poll) ----
#pragma unroll
            for (int q = 0; q < 4; ++q) {
                int kt = (mem << 2) + q;
                f16x8 a = readA(hstage, c, kt * 4 + g);
                if (q & 1) {
                    a0b = __builtin_amdgcn_mfma_f32_16x16x32_f16(a, wb0[q], a0b, 0, 0, 0);
                    a1b = __builtin_amdgcn_mfma_f32_16x16x32_f16(a, wb1[q], a1b, 0, 0, 0);
                } else {
                    a0a = __builtin_amdgcn_mfma_f32_16x16x32_f16(a, wb0[q], a0a, 0, 0, 0);
                    a1a = __builtin_amdgcn_mfma_f32_16x16x32_f16(a, wb1[q], a1a, 0, 0, 0);
                }
            }
            // ---- wave0 lanes<4 poll teammate flags (padded to 128B each) ----
            if (w == 0 && lane < 4) {
                while (__hip_atomic_load(&ready[(tslot + lane) * 32],
                                         __ATOMIC_RELAXED,
                                         __HIP_MEMORY_SCOPE_AGENT) < s) { }
            }
            __syncthreads();

            // ---- cooperative single-copy remote load (bypass L1/L2) ----
            i32x4 rv0, rv1, rv2;
            const f16* hin = hbuf + (size_t)(s & 1) * (B_SZ * H_SZ)
                                  + (size_t)(bt + prow) * H_SZ + pcg * 8;
            {
                const f16* p0 = hin + (((mem + 1) & 3) * SLICE);
                const f16* p1 = hin + (((mem + 2) & 3) * SLICE);
                const f16* p2 = hin + (((mem + 3) & 3) * SLICE);
                asm volatile("global_load_dwordx4 %0, %1, off sc0 sc1" : "=v"(rv0) : "v"(p0) : "memory");
                asm volatile("global_load_dwordx4 %0, %1, off sc0 sc1" : "=v"(rv1) : "v"(p1) : "memory");
                asm volatile("global_load_dwordx4 %0, %1, off sc0 sc1" : "=v"(rv2) : "v"(p2) : "memory");
            }
            asm volatile("s_waitcnt vmcnt(0)" ::: "memory");
            {
                int k0 = ((((mem + 1) & 3) * 16 + pcg) ^ (prow & 7)) * 8;
                int k1 = ((((mem + 2) & 3) * 16 + pcg) ^ (prow & 7)) * 8;
                int k2 = ((((mem + 3) & 3) * 16 + pcg) ^ (prow & 7)) * 8;
                *(i32x4*)&hstage[prow * H_SZ + k0] = rv0;
                *(i32x4*)&hstage[prow * H_SZ + k1] = rv1;
                *(i32x4*)&hstage[prow * H_SZ + k2] = rv2;
            }
            __syncthreads();

            // ---- remote-k MFMAs ----
#pragma unroll
            for (int q = 4; q < 16; ++q) {
                int kt = (((mem + (q >> 2)) & 3) << 2) + (q & 3);
                f16x8 a = readA(hstage, c, kt * 4 + g);
                if (q & 1) {
                    a0b = __builtin_amdgcn_mfma_f32_16x16x32_f16(a, wb0[q], a0b, 0, 0, 0);
                    a1b = __builtin_amdgcn_mfma_f32_16x16x32_f16(a, wb1[q], a1b, 0, 0, 0);
                } else {
                    a0a = __builtin_amdgcn_mfma_f32_16x16x32_f16(a, wb0[q], a0a, 0, 0, 0);
                    a1a = __builtin_amdgcn_mfma_f32_16x16x32_f16(a, wb1[q], a1a, 0, 0, 0);
                }
            }
        }

        // ---- tanh + stage own h_{s+1} into hstage (disjoint from remote reads) ----
#pragma unroll
        for (int nt = 0; nt < 2; ++nt) {
            f32x4 acc;
            if (nt == 0) { acc = a0a + a0b; } else { acc = a1a + a1b; }
            int col = jg0 + jrow0 + nt * 16 + c;
#pragma unroll
            for (int r = 0; r < 4; ++r) {
                float pre = acc[r] + biasv[nt];
                float e = __expf(2.f * pre);
                float hv = 1.f - 2.f * __builtin_amdgcn_rcpf(e + 1.f);
                int row = g * 4 + r;
                hstage[row * H_SZ + (col ^ ((row & 7) << 3))] = (f16)hv;
            }
        }
        __syncthreads();

        // ---- coalesced publish: one 16B sc0 sc1 store per thread ----
        {
            int k8 = ((mem * 16 + pcg) ^ (prow & 7)) * 8;
            i32x4 pv = *(const i32x4*)&hstage[prow * H_SZ + k8];
            f16* hout = hbuf + (size_t)((s + 1) & 1) * (B_SZ * H_SZ)
                             + (size_t)(bt + prow) * H_SZ + jg0 + pcg * 8;
            asm volatile("global_store_dwordx4 %0, %1, off sc0 sc1" :: "v"(hout), "v"(pv) : "memory");
        }
        asm volatile("s_waitcnt vmcnt(0)" ::: "memory");
        __syncthreads();
        if (tid == 0) {
            int* fp = &ready[(tslot + mem) * 32];
            int v = s + 1;
            asm volatile("global_store_dword %0, %1, off sc0 sc1" :: "v"(fp), "v"(v) : "memory");
        }
    }
}

// out[b][o] = sum_k h[b][k] * Wfc[o][k] + bfc[o]
__global__ __launch_bounds__(128) void fc_kernel(
    const f16* __restrict__ hbuf, const float* __restrict__ Wfc,
    const float* __restrict__ bfc, float* __restrict__ out)
{
    __builtin_amdgcn_fence(__ATOMIC_ACQUIRE, "agent");  // rnn wrote h via sc0 sc1
    __shared__ float hs[H_SZ];
    int b = blockIdx.x, o = threadIdx.x;
    for (int k = o; k < H_SZ; k += 128)
        hs[k] = (float)hbuf[(size_t)b * H_SZ + k];
    __syncthreads();
    const float* wr = Wfc + (size_t)o * H_SZ;
    float acc = bfc[o];
#pragma unroll 8
    for (int k = 0; k < H_SZ; k += 4) {
        float4 wv = *(const float4*)(wr + k);
        acc += wv.x * hs[k] + wv.y * hs[k + 1] + wv.z * hs[k + 2] + wv.w * hs[k + 3];
    }
    out[(size_t)b * O_SZ + o] = acc;
}

extern "C" void kernel_launch(void* const* d_in, const int* in_sizes, int n_in,
                              void* d_out, int out_size, void* d_ws, size_t ws_size,
                              hipStream_t stream) {
    const float* x   = (const float*)d_in[0];
    const float* Wih = (const float*)d_in[1];
    const float* Whh = (const float*)d_in[2];
    const float* bih = (const float*)d_in[3];
    const float* bhh = (const float*)d_in[4];
    const float* Wfc = (const float*)d_in[5];
    const float* bfc = (const float*)d_in[6];
    float* out = (float*)d_out;

    int* ready = (int*)d_ws;                       // 64 flags x 128B pad = 8KB
    f16* hbuf  = (f16*)((char*)d_ws + 8192);       // 2 x 256 x 512 f16 = 512KB

    (void)hipMemsetAsync(d_ws, 0, 8192, stream);   // zero flags each launch
    hipLaunchKernelGGL(rnn_kernel, dim3(64), dim3(256), 0, stream,
                       x, Wih, Whh, bih, bhh, hbuf, ready);
    hipLaunchKernelGGL(fc_kernel, dim3(B_SZ), dim3(128), 0, stream,
                       hbuf, Wfc, bfc, out);
}